// Round 6
// baseline (52.549 us; speedup 1.0000x reference)
//
#include <hip/hip_runtime.h>
#include <math.h>
#include <utility>

#define DIMS  16
#define BATCH 32768
#define NPAIR 136
#define NMT   5        // M-tiles of 32 (rows 0..159)
#define NKK   10       // K-steps of 16 (K = 160)
#define A_ELEMS (NKK*NMT*64*8)   // 25600 bf16, fragment-sliced
#define A_BYTES (A_ELEMS*2)      // 51200 B

typedef short s16x8  __attribute__((ext_vector_type(8)));
typedef float f32x16 __attribute__((ext_vector_type(16)));

// ---------- compile-time combinatorics (lex = combinations_with_replacement) ----------
constexpr int pairlex(int i0, int i1){ int s=0; for(int j=0;j<i0;++j) s+=(DIMS-j); return s+(i1-i0); }
constexpr int pid_i0(int pid){ int i0=0,rem=pid; while(rem>=DIMS-i0){rem-=DIMS-i0;++i0;} return i0; }
constexpr int pid_i1(int pid){ int i0=0,rem=pid; while(rem>=DIMS-i0){rem-=DIMS-i0;++i0;} return i0+rem; }
constexpr int cnt3(int j){ return (DIMS-j)*(DIMS+1-j)/2; }
constexpr int off3(int i0){ int s=0; for(int j=0;j<i0;++j) s+=cnt3(j); return s; }
constexpr int cnt4j(int j){ return (DIMS-j)*(DIMS+1-j)*(DIMS+2-j)/6; }
constexpr int off4(int i0){ int s=0; for(int j=0;j<i0;++j) s+=cnt4j(j); return s; }
// W layout: [0]=const, [1..16]=deg1, [17..152]=deg2, [153..968]=deg3, [969..4844]=deg4
constexpr int w3rowbase(int i0){ return 1+DIMS+NPAIR+off3(i0); }
constexpr int w4base(int i0,int i1){ int s=off4(i0); for(int b=i0;b<i1;++b) s+=cnt3(b); return 1+DIMS+NPAIR+816+s; }
static_assert(pairlex(15,15)==135 && off3(DIMS)==816 && off4(DIMS)==3876, "combi");
static_assert(w4base(15,15)==4844, "wtail");

// ---------- row metadata (r3/r5-verified): A[row][k] = gate*W[wb+k-qs] for qs<=k<qe ----------
struct RowMeta { short qs, qe, wb, deg; };
struct RowTab  { RowMeta m[NMT*32]; };
constexpr RowTab make_rowtab(){
    RowTab t{};
    for (int r = 0; r < NMT*32; ++r) {
        RowMeta rm{0,0,0,0};
        if (r < NPAIR) {                       // S4 rows
            int i0 = pid_i0(r), i1 = pid_i1(r);
            rm = RowMeta{ (short)pairlex(i1,i1), (short)NPAIR, (short)w4base(i0,i1), 4 };
        } else if (r < NPAIR + DIMS) {         // S3 rows
            int i0 = r - NPAIR;
            rm = RowMeta{ (short)pairlex(i0,i0), (short)NPAIR, (short)w3rowbase(i0), 3 };
        } else if (r == 152) {                 // S2 row
            rm = RowMeta{ 0, (short)NPAIR, (short)(1+DIMS), 2 };
        } else if (r == 153) {                 // S1 row
            rm = RowMeta{ (short)NPAIR, (short)(NPAIR+DIMS), 1, 1 };
        }
        t.m[r] = rm;
    }
    return t;
}

// ---------- DESC: A-slot (fragment layout) -> (deg<<13 | W index); 0 => zero ----------
struct DescT { unsigned short d[A_ELEMS]; };
constexpr DescT make_desc(){
    DescT D{};
    const RowTab rt = make_rowtab();
    for (int id = 0; id < A_ELEMS; ++id) {
        const int e = id & 7, ln = (id >> 3) & 63, mtkk = id >> 9;
        const int mt = mtkk % NMT, kk = mtkk / NMT;
        const int row = mt*32 + (ln & 31);
        const int k   = kk*16 + 4*(ln >> 5) + (e & 3) + 8*(e >> 2);
        const RowMeta rm = rt.m[row];
        unsigned short v = 0;
        if (k >= rm.qs && k < rm.qe)
            v = (unsigned short)(((unsigned)rm.deg << 13) | (unsigned)(rm.wb + k - rm.qs));
        D.d[id] = v;
    }
    return D;
}
__device__ __constant__ DescT DESC = make_desc();

// ---------- helpers ----------
__device__ __forceinline__ ushort f2bf(float f){
    union { float f; unsigned u; } v{f};
    return (ushort)((v.u + 0x7FFF + ((v.u >> 16) & 1)) >> 16);   // RNE
}
__device__ __forceinline__ unsigned packbf(float a, float b){    // round-to-nearest pack
    const unsigned ua = __float_as_uint(a) + 0x8000u;
    const unsigned ub = __float_as_uint(b) + 0x8000u;
    return (ua >> 16) | (ub & 0xFFFF0000u);
}

template<typename F, int... Is>
__device__ __forceinline__ void sfor_impl(F&& f, std::integer_sequence<int,Is...>){
    (f(std::integral_constant<int,Is>{}), ...);
}
template<int N, typename F>
__device__ __forceinline__ void sfor(F&& f){
    sfor_impl(static_cast<F&&>(f), std::make_integer_sequence<int,N>{});
}

// F row value (static row -> static xv indices)
template<int R>
__device__ __forceinline__ float fval(const float (&xv)[DIMS]){
    if constexpr      (R < NPAIR)        return xv[pid_i0(R)] * xv[pid_i1(R)];
    else if constexpr (R < NPAIR+DIMS)   return xv[R - NPAIR];
    else if constexpr (R < 154)          return 1.0f;
    else                                 return 0.0f;
}

// ---------- kernel 1: build gated A (sample-independent) into d_ws ----------
__global__ __launch_bounds__(256)
void build_A_kernel(const float* __restrict__ W, const float* __restrict__ M_raw,
                    unsigned* __restrict__ A_ws)
{
    const int t = blockIdx.x*256 + threadIdx.x;          // 0..12799
    const float M  = 3.0f/(1.0f+__expf(-M_raw[0])) + 1.0f;
    const float g1 = 1.0f/(1.0f+__expf(-10.0f*(M-0.5f)));
    const float g2 = 1.0f/(1.0f+__expf(-10.0f*(M-1.5f)));
    const float g3 = 1.0f/(1.0f+__expf(-10.0f*(M-2.5f)));
    const float g4 = 1.0f/(1.0f+__expf(-10.0f*(M-3.5f)));

    const unsigned d  = reinterpret_cast<const unsigned*>(DESC.d)[t];
    const unsigned d0 = d & 0xFFFFu, d1 = d >> 16;
    const int deg0 = d0 >> 13, deg1 = d1 >> 13;
    const float gv0 = deg0==4?g4 : deg0==3?g3 : deg0==2?g2 : deg0==1?g1 : 0.0f;
    const float gv1 = deg1==4?g4 : deg1==3?g3 : deg1==2?g2 : deg1==1?g1 : 0.0f;
    const float v0 = gv0 * W[d0 & 0x1FFF];
    const float v1 = gv1 * W[d1 & 0x1FFF];
    A_ws[t] = (unsigned)f2bf(v0) | ((unsigned)f2bf(v1) << 16);
}

// ---------- main GEMM: per half-wave mt set, acc + epilogue fully in-register ----------
template<int MT0, int NL>
__device__ __forceinline__ float run_half(const ushort* __restrict__ A_sh,
                                          const unsigned (&bfw)[NKK][4], int lane)
{
    f32x16 acc[NL] = {};
    sfor<NKK>([&](auto K){ constexpr int kk = decltype(K)::value;
        union { unsigned u[4]; s16x8 v; } bu;
        bu.u[0]=bfw[kk][0]; bu.u[1]=bfw[kk][1]; bu.u[2]=bfw[kk][2]; bu.u[3]=bfw[kk][3];
        sfor<NL>([&](auto Mc){ constexpr int m = decltype(Mc)::value;
            const s16x8 af = *reinterpret_cast<const s16x8*>(
                A_sh + (size_t)((kk*NMT + MT0 + m)*64 + lane)*8);
            acc[m] = __builtin_amdgcn_mfma_f32_32x32x16_bf16(af, bu.v, acc[m], 0, 0, 0);
        });
    });
    // epilogue: mult = F[32mt + crow][col] read from the wave's own B-frag registers
    // C/D: col=lane&31, row=(reg&3)+8*(reg>>2)+4*(lane>>5)  (r5-verified)
    float ptot = 0.0f;
    sfor<NL>([&](auto Mc){ constexpr int m = decltype(Mc)::value;
        float p = 0.0f;
        sfor<16>([&](auto R){ constexpr int reg = decltype(R)::value;
            constexpr int kksel = 2*(MT0 + m) + (reg >> 3);
            constexpr int word  = ((reg & 3) >> 1) + 2*((reg >> 2) & 1);
            const unsigned w = bfw[kksel][word];
            const float mult = __uint_as_float((reg & 1) ? (w & 0xFFFF0000u) : (w << 16));
            p = fmaf(mult, acc[m][reg], p);
        });
        p += __shfl_xor(p, 32);          // combine h-halves (row halves)
        ptot += p;
    });
    return ptot;
}

// Grid 256 x 512 thr (8 waves = 4 sample-groups x 2 mt-halves). LDS: A 50K + red 0.5K.
__global__ __launch_bounds__(512, 2)
void poly_logreg_mfma3(const float* __restrict__ x, const float* __restrict__ W,
                       const float* __restrict__ b, const unsigned* __restrict__ A_ws,
                       float* __restrict__ out)
{
    __shared__ __align__(16) ushort A_sh[A_ELEMS];
    __shared__ float red[4][32];

    const int t = threadIdx.x, lane = t & 63, wv = t >> 6;
    const int group = wv >> 1, half = wv & 1;
    const int col = lane & 31;
    const bool hs = lane >= 32;
    const int s0 = blockIdx.x*128 + group*32;

    // ---- issue x loads (consumed by F-build) ----
    const float4* xp = reinterpret_cast<const float4*>(x + (size_t)(s0 + col)*DIMS);
    const float4 xa = xp[0], xb = xp[1], xc = xp[2], xd = xp[3];

    // ---- issue A staging loads (coalesced 16B; written to LDS after F-build) ----
    uint4 st[6];
    #pragma unroll
    for (int i = 0; i < 6; ++i)
        st[i] = reinterpret_cast<const uint4*>(A_ws)[i*512 + t];
    const unsigned stt = A_ws[12288 + t];

    // ---- F-build: 80 rows for this lane's h, packed bf16 pairs, all static ----
    float xv[DIMS];
    xv[0]=xa.x; xv[1]=xa.y; xv[2]=xa.z; xv[3]=xa.w;
    xv[4]=xb.x; xv[5]=xb.y; xv[6]=xb.z; xv[7]=xb.w;
    xv[8]=xc.x; xv[9]=xc.y; xv[10]=xc.z; xv[11]=xc.w;
    xv[12]=xd.x; xv[13]=xd.y; xv[14]=xd.z; xv[15]=xd.w;

    unsigned bfw[NKK][4];
    sfor<NKK>([&](auto K){ constexpr int kk = decltype(K)::value;
        sfor<4>([&](auto J){ constexpr int j = decltype(J)::value;
            constexpr int e0 = 2*j, e1 = 2*j + 1;
            constexpr int r0a = 16*kk + (e0 & 3) + 8*(e0 >> 2);
            constexpr int r0b = 16*kk + (e1 & 3) + 8*(e1 >> 2);
            const float va = hs ? fval<r0a+4>(xv) : fval<r0a>(xv);
            const float vb = hs ? fval<r0b+4>(xv) : fval<r0b>(xv);
            bfw[kk][j] = packbf(va, vb);
        });
    });

    // ---- write staged A to LDS, barrier ----
    #pragma unroll
    for (int i = 0; i < 6; ++i)
        reinterpret_cast<uint4*>(A_sh)[i*512 + t] = st[i];
    reinterpret_cast<unsigned*>(A_sh)[12288 + t] = stt;
    __syncthreads();

    // ---- MFMA + in-register epilogue ----
    float ptot;
    if (half == 0) ptot = run_half<0, 3>(A_sh, bfw, lane);
    else           ptot = run_half<3, 2>(A_sh, bfw, lane);

    // ---- combine halves, finalize ----
    if (half == 1 && lane < 32) red[group][lane] = ptot;
    __syncthreads();
    if (half == 0 && lane < 32) {
        const float logit = ptot + red[group][lane] + W[0] + b[0];
        out[s0 + lane] = 1.0f/(1.0f+__expf(-logit));
    }
}

extern "C" void kernel_launch(void* const* d_in, const int* in_sizes, int n_in,
                              void* d_out, int out_size, void* d_ws, size_t ws_size,
                              hipStream_t stream)
{
    const float* x     = (const float*)d_in[0];
    const float* W     = (const float*)d_in[1];
    const float* b     = (const float*)d_in[2];
    const float* M_raw = (const float*)d_in[3];
    float* out = (float*)d_out;
    unsigned* A_ws = (unsigned*)d_ws;            // needs 51200 B

    build_A_kernel<<<A_ELEMS/512, 256, 0, stream>>>(W, M_raw, A_ws);
    poly_logreg_mfma3<<<BATCH/128, 512, 0, stream>>>(x, W, b, A_ws, out);
}

// Round 7
// 29.536 us; speedup vs baseline: 1.7791x; 1.7791x over previous
//
#include <hip/hip_runtime.h>
#include <math.h>
#include <utility>

#define DIMS  16
#define BATCH 32768
#define NPAIR 136
#define NB    128      // samples per block
#define NMT   5        // M-tiles of 32 (rows 0..159)
#define NNT   4        // N-tiles of 32 (128 samples)
#define NKK   10       // K-steps of 16 (K = 160)

typedef short s16x8  __attribute__((ext_vector_type(8)));
typedef float f32x16 __attribute__((ext_vector_type(16)));

#define A_ELEMS (NKK*NMT*64*8)       // 25600 bf16, fragment-sliced
#define A_BYTES (A_ELEMS*2)          // 51200
#define P_ELEMS (NKK*NNT*64*8)       // 20480 bf16
#define P_BYTES (P_ELEMS*2)          // 40960
#define RED_OFF (A_BYTES+P_BYTES)    // 92160
#define LDS_BYTES (RED_OFF + NMT*NNT*32*4)   // 94720 B -> 1 block/CU

// ---------- compile-time combinatorics (lex = combinations_with_replacement) ----------
constexpr int pairlex(int i0, int i1){ int s=0; for(int j=0;j<i0;++j) s+=(DIMS-j); return s+(i1-i0); }
constexpr int pid_i0(int pid){ int i0=0,rem=pid; while(rem>=DIMS-i0){rem-=DIMS-i0;++i0;} return i0; }
constexpr int pid_i1(int pid){ int i0=0,rem=pid; while(rem>=DIMS-i0){rem-=DIMS-i0;++i0;} return i0+rem; }
constexpr int cnt3(int j){ return (DIMS-j)*(DIMS+1-j)/2; }
constexpr int off3(int i0){ int s=0; for(int j=0;j<i0;++j) s+=cnt3(j); return s; }
constexpr int cnt4j(int j){ return (DIMS-j)*(DIMS+1-j)*(DIMS+2-j)/6; }
constexpr int off4(int i0){ int s=0; for(int j=0;j<i0;++j) s+=cnt4j(j); return s; }
// W layout: [0]=const, [1..16]=deg1, [17..152]=deg2, [153..968]=deg3, [969..4844]=deg4
constexpr int w3rowbase(int i0){ return 1+DIMS+NPAIR+off3(i0); }
constexpr int w4base(int i0,int i1){ int s=off4(i0); for(int b=i0;b<i1;++b) s+=cnt3(b); return 1+DIMS+NPAIR+816+s; }
static_assert(pairlex(15,15)==135 && off3(DIMS)==816 && off4(DIMS)==3876, "combi");
static_assert(w4base(15,15)==4844, "wtail");

// ---------- row metadata (r3/r5/r6-verified): A[row][k] = gate*W[wb+k-qs] for qs<=k<qe ----------
struct RowMeta { short qs, qe, wb, deg; };
struct RowTab  { RowMeta m[NMT*32]; };
constexpr RowTab make_rowtab(){
    RowTab t{};
    for (int r = 0; r < NMT*32; ++r) {
        RowMeta rm{0,0,0,0};
        if (r < NPAIR) {
            int i0 = pid_i0(r), i1 = pid_i1(r);
            rm = RowMeta{ (short)pairlex(i1,i1), (short)NPAIR, (short)w4base(i0,i1), 4 };
        } else if (r < NPAIR + DIMS) {
            int i0 = r - NPAIR;
            rm = RowMeta{ (short)pairlex(i0,i0), (short)NPAIR, (short)w3rowbase(i0), 3 };
        } else if (r == 152) {
            rm = RowMeta{ 0, (short)NPAIR, (short)(1+DIMS), 2 };
        } else if (r == 153) {
            rm = RowMeta{ (short)NPAIR, (short)(NPAIR+DIMS), 1, 1 };
        }
        t.m[r] = rm;
    }
    return t;
}

// ---------- DESC: A-slot (fragment layout) -> (deg<<13 | W index); 0 => zero ----------
struct DescT { unsigned short d[A_ELEMS]; };
constexpr DescT make_desc(){
    DescT D{};
    const RowTab rt = make_rowtab();
    for (int id = 0; id < A_ELEMS; ++id) {
        const int e = id & 7, ln = (id >> 3) & 63, mtkk = id >> 9;
        const int mt = mtkk % NMT, kk = mtkk / NMT;
        const int row = mt*32 + (ln & 31);
        const int k   = kk*16 + 4*(ln >> 5) + (e & 3) + 8*(e >> 2);
        const RowMeta rm = rt.m[row];
        unsigned short v = 0;
        if (k >= rm.qs && k < rm.qe)
            v = (unsigned short)(((unsigned)rm.deg << 13) | (unsigned)(rm.wb + k - rm.qs));
        D.d[id] = v;
    }
    return D;
}
__device__ __constant__ DescT DESC = make_desc();

// ---------- helpers ----------
__device__ __forceinline__ ushort f2bf(float f){
    union { float f; unsigned u; } v{f};
    return (ushort)((v.u + 0x7FFF + ((v.u >> 16) & 1)) >> 16);   // RNE
}

template<typename F, int... Is>
__device__ __forceinline__ void sfor_impl(F&& f, std::integer_sequence<int,Is...>){
    (f(std::integral_constant<int,Is>{}), ...);
}
template<int N, typename F>
__device__ __forceinline__ void sfor(F&& f){
    sfor_impl(static_cast<F&&>(f), std::make_integer_sequence<int,N>{});
}

// F row value (static row -> static xv indices)
template<int R>
__device__ __forceinline__ float fval(const float (&xv)[DIMS]){
    if constexpr      (R < NPAIR)        return xv[pid_i0(R)] * xv[pid_i1(R)];
    else if constexpr (R < NPAIR+DIMS)   return xv[R - NPAIR];
    else if constexpr (R < 154)          return 1.0f;
    else                                 return 0.0f;
}

// pack 8 rows of F for (frag kk, half h) into one b128 LDS write (r5-verified).
// B-frag: lane l -> n=l&31, k_inner = 4*(l>>5)+(e&3)+8*(e>>2)
template<int KK, int H>
__device__ __forceinline__ void emitF(ushort* __restrict__ P_sh, int s, const float (&xv)[DIMS]){
    s16x8 v;
    sfor<8>([&](auto E){ constexpr int e = decltype(E)::value;
        constexpr int row = 16*KK + 4*H + (e & 3) + 8*(e >> 2);
        v[e] = (short)f2bf(fval<row>(xv)); });
    const int nt = s >> 5, l = (s & 31) + 32*H;
    *reinterpret_cast<s16x8*>(P_sh + (size_t)((KK*NNT + nt)*64 + l)*8) = v;
}

template<int G>
__device__ __forceinline__ void buildF(ushort* __restrict__ P_sh, int s, const float (&xv)[DIMS]){
    emitF<2*G,   0>(P_sh, s, xv);
    emitF<2*G,   1>(P_sh, s, xv);
    emitF<2*G+1, 0>(P_sh, s, xv);
    emitF<2*G+1, 1>(P_sh, s, xv);
}

// ---------- kernel 1: build gated A (sample-independent) into d_ws ----------
__global__ __launch_bounds__(256)
void build_A_kernel(const float* __restrict__ W, const float* __restrict__ M_raw,
                    unsigned* __restrict__ A_ws)
{
    const int t = blockIdx.x*256 + threadIdx.x;          // 0..12799
    const float M  = 3.0f/(1.0f+__expf(-M_raw[0])) + 1.0f;
    const float g1 = 1.0f/(1.0f+__expf(-10.0f*(M-0.5f)));
    const float g2 = 1.0f/(1.0f+__expf(-10.0f*(M-1.5f)));
    const float g3 = 1.0f/(1.0f+__expf(-10.0f*(M-2.5f)));
    const float g4 = 1.0f/(1.0f+__expf(-10.0f*(M-3.5f)));

    const unsigned d  = reinterpret_cast<const unsigned*>(DESC.d)[t];
    const unsigned d0 = d & 0xFFFFu, d1 = d >> 16;
    const int deg0 = d0 >> 13, deg1 = d1 >> 13;
    const float gv0 = deg0==4?g4 : deg0==3?g3 : deg0==2?g2 : deg0==1?g1 : 0.0f;
    const float gv1 = deg1==4?g4 : deg1==3?g3 : deg1==2?g2 : deg1==1?g1 : 0.0f;
    const float v0 = gv0 * W[d0 & 0x1FFF];
    const float v1 = gv1 * W[d1 & 0x1FFF];
    A_ws[t] = (unsigned)f2bf(v0) | ((unsigned)f2bf(v1) << 16);
}

// ---------- kernel 2: 640 thr = 10 waves, 128 samples/block, 20 tiles x 1 wave each x2 ----------
// ZERO fragment arrays: acc(16 VGPR) is the only persistent register state per tile.
__global__ __launch_bounds__(640, 1)
void poly_logreg_mfma4(const float* __restrict__ x, const float* __restrict__ W,
                       const float* __restrict__ b, const unsigned* __restrict__ A_ws,
                       float* __restrict__ out)
{
    extern __shared__ char smem[];
    ushort* A_sh = reinterpret_cast<ushort*>(smem);
    ushort* P_sh = reinterpret_cast<ushort*>(smem + A_BYTES);
    float*  red  = reinterpret_cast<float*>(smem + RED_OFF);

    const int t = threadIdx.x, lane = t & 63, wv = t >> 6;
    const int s = t & (NB - 1);                 // sample 0..127
    const int g = t >> 7;                       // F row-group 0..4 (wave-uniform)

    // ---- issue x loads ----
    const float4* xp = reinterpret_cast<const float4*>(
        x + ((size_t)blockIdx.x * NB + s) * DIMS);
    const float4 xa = xp[0], xb = xp[1], xc = xp[2], xd = xp[3];

    // ---- issue A staging loads (5 x uint4/thread, coalesced; die at barrier) ----
    uint4 st[5];
    #pragma unroll
    for (int i = 0; i < 5; ++i)
        st[i] = reinterpret_cast<const uint4*>(A_ws)[i*640 + t];

    // ---- F-build into LDS (r5-verified path) ----
    float xv[DIMS];
    xv[0]=xa.x; xv[1]=xa.y; xv[2]=xa.z; xv[3]=xa.w;
    xv[4]=xb.x; xv[5]=xb.y; xv[6]=xb.z; xv[7]=xb.w;
    xv[8]=xc.x; xv[9]=xc.y; xv[10]=xc.z; xv[11]=xc.w;
    xv[12]=xd.x; xv[13]=xd.y; xv[14]=xd.z; xv[15]=xd.w;
    switch (g) {
        case 0:  buildF<0>(P_sh, s, xv); break;
        case 1:  buildF<1>(P_sh, s, xv); break;
        case 2:  buildF<2>(P_sh, s, xv); break;
        case 3:  buildF<3>(P_sh, s, xv); break;
        default: buildF<4>(P_sh, s, xv); break;
    }

    // ---- write staged A to LDS ----
    #pragma unroll
    for (int i = 0; i < 5; ++i)
        reinterpret_cast<uint4*>(A_sh)[i*640 + t] = st[i];
    __syncthreads();

    // ---- GEMM: wave wv owns tiles 2wv, 2wv+1 (runtime mt/nt -> one code path) ----
    #pragma unroll
    for (int j = 0; j < 2; ++j) {
        const int ti = 2*wv + j, mt = ti >> 2, nt = ti & 3;

        f32x16 acc = {};
        #pragma unroll
        for (int kk = 0; kk < NKK; ++kk) {
            const s16x8 af = *reinterpret_cast<const s16x8*>(
                A_sh + (size_t)((kk*NMT + mt)*64 + lane)*8);
            const s16x8 bf = *reinterpret_cast<const s16x8*>(
                P_sh + (size_t)((kk*NNT + nt)*64 + lane)*8);
            acc = __builtin_amdgcn_mfma_f32_32x32x16_bf16(af, bf, acc, 0, 0, 0);
        }

        // epilogue: 16 multipliers F[32mt+crow][32nt+col] == this lane's own two
        // B-frag words at kk = 2mt, 2mt+1 -> two contiguous b128 LDS reads.
        // (index algebra: l==lane, e=(reg&3)+4*((reg>>2)&1), word = reg<8 ? m0 : m1)
        const ushort* mb = P_sh + (size_t)(((2*mt)*NNT + nt)*64 + lane)*8;
        const uint4 m0 = *reinterpret_cast<const uint4*>(mb);
        const uint4 m1 = *reinterpret_cast<const uint4*>(mb + 2048);

        float p = 0.0f;
        sfor<16>([&](auto R){ constexpr int reg = decltype(R)::value;
            constexpr int e = (reg & 3) + 4*((reg >> 2) & 1);
            unsigned w;
            if constexpr (reg < 8) w = (e>>1)==0 ? m0.x : (e>>1)==1 ? m0.y : (e>>1)==2 ? m0.z : m0.w;
            else                   w = (e>>1)==0 ? m1.x : (e>>1)==1 ? m1.y : (e>>1)==2 ? m1.z : m1.w;
            const float mult = __uint_as_float((e & 1) ? (w & 0xFFFF0000u) : (w << 16));
            p = fmaf(mult, acc[reg], p);
        });
        p += __shfl_xor(p, 32);          // combine the two lane-half row-sets
        if (lane < 32) red[ti*32 + lane] = p;
    }
    __syncthreads();

    // ---- finalize 128 samples ----
    if (t < NB) {
        const int nt = t >> 5, c = t & 31;
        float logit = W[0] + b[0];
        #pragma unroll
        for (int mt = 0; mt < NMT; ++mt) logit += red[(mt*NNT + nt)*32 + c];
        out[(size_t)blockIdx.x * NB + t] = 1.0f/(1.0f+__expf(-logit));
    }
}

extern "C" void kernel_launch(void* const* d_in, const int* in_sizes, int n_in,
                              void* d_out, int out_size, void* d_ws, size_t ws_size,
                              hipStream_t stream)
{
    const float* x     = (const float*)d_in[0];
    const float* W     = (const float*)d_in[1];
    const float* b     = (const float*)d_in[2];
    const float* M_raw = (const float*)d_in[3];
    float* out = (float*)d_out;
    unsigned* A_ws = (unsigned*)d_ws;            // 51200 B

    build_A_kernel<<<A_ELEMS/512, 256, 0, stream>>>(W, M_raw, A_ws);
    poly_logreg_mfma4<<<BATCH/NB, 640, LDS_BYTES, stream>>>(x, W, b, A_ws, out);
}